// Round 5
// baseline (61.962 us; speedup 1.0000x reference)
//
#include <hip/hip_runtime.h>
#include <hip/hip_bf16.h>

#define B_   16
#define L_   256
#define D_   512
#define C_   8
#define P_   12
#define LOUT 244
#define O_   512
#define GM   3904   // 61*64 exactly
#define BM   64
#define BN   256
#define BK   64
#define NMT  61
#define NNT  2

typedef __attribute__((ext_vector_type(8))) short bf16x8;
typedef __attribute__((ext_vector_type(4))) float f32x4;
typedef __attribute__((ext_vector_type(2))) float f32x2;

__device__ __forceinline__ unsigned short f2bf(float f) {
    unsigned int u = __float_as_uint(f);
    unsigned int r = (u + 0x7FFFu + ((u >> 16) & 1u)) >> 16;
    return (unsigned short)r;
}

__device__ __forceinline__ void async_copy16(const void* g, void* l) {
    __builtin_amdgcn_global_load_lds(
        (const __attribute__((address_space(1))) unsigned int*)g,
        (__attribute__((address_space(3))) unsigned int*)l, 16, 0, 0);
}

// ---------------------------------------------------------------------------
// wsb convert: Ws f32 -> bf16 (one float4 per thread)
// ---------------------------------------------------------------------------
__global__ __launch_bounds__(256) void ws_convert(const float* __restrict__ Ws,
                                                  unsigned short* __restrict__ wsb) {
    int g = blockIdx.x * 256 + threadIdx.x;   // 524288 float4s
    float4 v = ((const float4*)Ws)[g];
    ushort4 o;
    o.x = f2bf(v.x); o.y = f2bf(v.y); o.z = f2bf(v.z); o.w = f2bf(v.w);
    ((ushort4*)wsb)[g] = o;
}

// ---------------------------------------------------------------------------
// fused, 2-phase dbuf + PINNED issue order:
//   per K-step: {STAGE_B(t+1) async, FIR_LOAD(t+1)} -> mem-fence (loads cannot
//   sink) -> MFMA(t) -> FIR pk-fma + ds_write(t+1) (vmcnt waits land here,
//   under the MFMA shadow) -> one __syncthreads.
//   BM=64, BN=256, BK=64, 512 thr = 8 waves (2M x 4N), wave tile 32x64.
//   LDS 80 KB dbuf -> 2 blocks/CU. XOR swizzle (16B chunk ^ row&7): B
//   pre-swizzled at global source (linear dest, rule 21), A at ds_write.
//   bid = (c*2+nt)*61 + mt: consecutive bids share B panel across XCD stripe.
// ---------------------------------------------------------------------------
__global__ __launch_bounds__(512, 4) void fused(const float* __restrict__ inp,
                                                const unsigned short* __restrict__ wsb,
                                                const float* __restrict__ bs,
                                                const float* __restrict__ Wt,
                                                const float* __restrict__ bt,
                                                float* __restrict__ out) {
    __shared__ unsigned short As0[BM * BK], As1[BM * BK];
    __shared__ unsigned short Bs0[BN * BK], Bs1[BN * BK];

    int bid = blockIdx.x;
    int mt = bid % NMT;
    int t2 = bid / NMT;
    int nt = t2 & 1;
    int c  = t2 >> 1;
    int row0 = mt * BM;
    int tid = threadIdx.x, lane = tid & 63, wid = tid >> 6;
    int wm = wid >> 2, wn = wid & 3;   // 2 x 4

    // FIR weights: wave-uniform -> SGPRs
    float w[P_];
#pragma unroll
    for (int p = 0; p < P_; ++p) w[p] = Wt[c * P_ + p];

    // FIR task: 4 consecutive rows (lq*4..+3), one d-pair (dp*2, dp*2+1).
    // 244 % 4 == 0 -> a 4-row group never crosses a batch boundary.
    int lq = tid >> 5;                 // 0..15
    int dp = tid & 31;                 // 0..31
    int rg = row0 + lq * 4;
    int fb = rg / LOUT, fl = rg % LOUT;   // fl+14 <= 254 < 256: in-bounds
    const float* fir_base = inp + ((size_t)fb * L_ + fl) * D_ + dp * 2;
    int awr[4];
#pragma unroll
    for (int j = 0; j < 4; ++j) {
        int rj = lq * 4 + j;
        awr[j] = rj * BK + ((((dp >> 2) ^ (rj & 7)) << 3) + ((dp & 3) << 1));
    }

    const unsigned short* Bb = wsb + ((size_t)c * O_ + nt * BN) * D_;

    f32x4 acc[2][4];
#pragma unroll
    for (int m = 0; m < 2; ++m)
#pragma unroll
        for (int n = 0; n < 4; ++n)
            acc[m][n] = (f32x4){0.f, 0.f, 0.f, 0.f};

    unsigned short *Ac = As0, *Bc = Bs0, *An = As1, *Bn = Bs1;

#define STAGE_B(dst, dcol)                                                    \
    _Pragma("unroll")                                                         \
    for (int h = 0; h < 4; ++h) {                                             \
        int q = h * 512 + tid;                                                \
        int brow = q >> 3, cc = q & 7;                                        \
        async_copy16(Bb + (size_t)brow * D_ + (dcol) + ((cc ^ (brow & 7)) << 3), \
                     (dst) + q * 8);                                          \
    }

#define FIR_LOAD(vv, dcol)                                                    \
    _Pragma("unroll")                                                         \
    for (int j = 0; j < 15; ++j)                                              \
        vv[j] = *(const f32x2*)(fir_base + (size_t)j * D_ + (dcol));

#define FIR_STORE(vv, dst)                                                    \
    _Pragma("unroll")                                                         \
    for (int j = 0; j < 4; ++j) {                                             \
        f32x2 s = (f32x2){0.f, 0.f};                                          \
        _Pragma("unroll")                                                     \
        for (int p = 0; p < P_; ++p)                                          \
            s += vv[j + p] * w[p];      /* v_pk_fma_f32 */                    \
        ushort2 ov; ov.x = f2bf(s.x); ov.y = f2bf(s.y);                       \
        *(ushort2*)&(dst)[awr[j]] = ov;                                       \
    }

#define MFMA_STEP(Asrc, Bsrc)                                                 \
    _Pragma("unroll")                                                         \
    for (int kk = 0; kk < 2; ++kk) {                                          \
        bf16x8 af[2], bq[4];                                                  \
        _Pragma("unroll")                                                     \
        for (int m = 0; m < 2; ++m) {                                         \
            int r = wm * 32 + m * 16 + (lane & 15);                           \
            af[m] = *(const bf16x8*)&(Asrc)[r * BK +                          \
                    (((kk * 4 + (lane >> 4)) ^ (r & 7)) << 3)];               \
        }                                                                     \
        _Pragma("unroll")                                                     \
        for (int n = 0; n < 4; ++n) {                                         \
            int o = wn * 64 + n * 16 + (lane & 15);                           \
            bq[n] = *(const bf16x8*)&(Bsrc)[o * BK +                          \
                    (((kk * 4 + (lane >> 4)) ^ (o & 7)) << 3)];               \
        }                                                                     \
        _Pragma("unroll")                                                     \
        for (int m = 0; m < 2; ++m)                                           \
            _Pragma("unroll")                                                 \
            for (int n = 0; n < 4; ++n)                                       \
                acc[m][n] = __builtin_amdgcn_mfma_f32_16x16x32_bf16(          \
                    af[m], bq[n], acc[m][n], 0, 0, 0);                        \
    }

    // ---- prologue: stage t=0 ----
    {
        STAGE_B(Bc, 0)
        f32x2 v[15];
        FIR_LOAD(v, 0)
        FIR_STORE(v, Ac)
    }
    __syncthreads();

    // ---- main loop: 7 pipelined steps ----
    for (int t = 0; t < 7; ++t) {
        int dn = (t + 1) * BK;
        STAGE_B(Bn, dn)                 // async DMA into next B buffer
        f32x2 v[15];
        FIR_LOAD(v, dn)                 // next-step FIR inputs
        // Pin: loads above may NOT sink below this point; their waitcnt
        // still lands at first use (FIR_STORE), i.e. under the MFMA shadow.
        asm volatile("" ::: "memory");
        MFMA_STEP(Ac, Bc)
        FIR_STORE(v, An)
        __syncthreads();
        unsigned short* tp;
        tp = Ac; Ac = An; An = tp;
        tp = Bc; Bc = Bn; Bn = tp;
    }

    // ---- epilogue: last K-step ----
    MFMA_STEP(Ac, Bc)

    // ---- bias + store ----
    float S = 0.f;
#pragma unroll
    for (int p = 0; p < P_; ++p) S += w[p];
    float btc = bt[c];

#pragma unroll
    for (int m = 0; m < 2; ++m) {
        int rb = row0 + wm * 32 + m * 16 + ((lane >> 4) << 2);
#pragma unroll
        for (int n = 0; n < 4; ++n) {
            int gcol = nt * BN + wn * 64 + n * 16 + (lane & 15);
            float add = bs[c * O_ + gcol] * S + btc;
#pragma unroll
            for (int i = 0; i < 4; ++i)
                out[((size_t)(rb + i) * C_ + c) * O_ + gcol] = acc[m][n][i] + add;
        }
    }
#undef STAGE_B
#undef FIR_LOAD
#undef FIR_STORE
#undef MFMA_STEP
}

// ---------------------------------------------------------------------------
// Fallback (ws too small): slow but correct, no workspace.
// ---------------------------------------------------------------------------
__global__ __launch_bounds__(256) void naive_k(const float* __restrict__ inp,
                                               const float* __restrict__ Ws,
                                               const float* __restrict__ bs,
                                               const float* __restrict__ Wt,
                                               const float* __restrict__ bt,
                                               float* __restrict__ out) {
    __shared__ float tmp[D_];
    int bid = blockIdx.x;
    int c = bid & 7; int r = bid >> 3;
    int l = r % LOUT; int b = r / LOUT;
    int tid = threadIdx.x;

    for (int d = tid; d < D_; d += 256) {
        float s = 0.f;
        for (int p = 0; p < P_; ++p)
            s += Wt[c * P_ + p] * inp[((size_t)b * L_ + l + p) * D_ + d];
        tmp[d] = s;
    }
    __syncthreads();
    float S = 0.f;
    for (int p = 0; p < P_; ++p) S += Wt[c * P_ + p];
    for (int o = tid; o < O_; o += 256) {
        const float* wrow = Ws + ((size_t)c * O_ + o) * D_;
        float s = 0.f;
        for (int d = 0; d < D_; ++d) s += wrow[d] * tmp[d];
        out[(((size_t)b * LOUT + l) * C_ + c) * O_ + o] =
            s + bs[c * O_ + o] * S + bt[c];
    }
}

extern "C" void kernel_launch(void* const* d_in, const int* in_sizes, int n_in,
                              void* d_out, int out_size, void* d_ws, size_t ws_size,
                              hipStream_t stream) {
    const float* inp = (const float*)d_in[0];
    const float* Ws  = (const float*)d_in[1];
    const float* bs  = (const float*)d_in[2];
    const float* Wt  = (const float*)d_in[3];
    const float* bt  = (const float*)d_in[4];
    float* out = (float*)d_out;

    const size_t WSBB = (size_t)C_ * O_ * D_ * 2;   // 4,194,304 bytes

    if (ws_size >= WSBB) {
        unsigned short* wsb = (unsigned short*)d_ws;
        ws_convert<<<2048, 256, 0, stream>>>(Ws, wsb);
        fused<<<NMT * NNT * C_, 512, 0, stream>>>(inp, wsb, bs, Wt, bt, out);
    } else {
        naive_k<<<B_ * LOUT * C_, 256, 0, stream>>>(inp, Ws, bs, Wt, bt, out);
    }
}

// Round 6
// 58.362 us; speedup vs baseline: 1.0617x; 1.0617x over previous
//
#include <hip/hip_runtime.h>
#include <hip/hip_bf16.h>

#define B_   16
#define L_   256
#define D_   512
#define C_   8
#define P_   12
#define LOUT 244
#define O_   512
#define GM   3904   // 61*64 exactly
#define BM   64
#define BN   256
#define BK   64
#define NMT  61
#define NNT  2

typedef __attribute__((ext_vector_type(8))) short bf16x8;
typedef __attribute__((ext_vector_type(4))) float f32x4;
typedef __attribute__((ext_vector_type(2))) float f32x2;

__device__ __forceinline__ unsigned short f2bf(float f) {
    unsigned int u = __float_as_uint(f);
    unsigned int r = (u + 0x7FFFu + ((u >> 16) & 1u)) >> 16;
    return (unsigned short)r;
}

__device__ __forceinline__ void async_copy16(const void* g, void* l) {
    __builtin_amdgcn_global_load_lds(
        (const __attribute__((address_space(1))) unsigned int*)g,
        (__attribute__((address_space(3))) unsigned int*)l, 16, 0, 0);
}

// ---------------------------------------------------------------------------
// wsb convert: Ws f32 -> bf16 (one float4 per thread)
// ---------------------------------------------------------------------------
__global__ __launch_bounds__(256) void ws_convert(const float* __restrict__ Ws,
                                                  unsigned short* __restrict__ wsb) {
    int g = blockIdx.x * 256 + threadIdx.x;   // 524288 float4s
    float4 v = ((const float4*)Ws)[g];
    ushort4 o;
    o.x = f2bf(v.x); o.y = f2bf(v.y); o.z = f2bf(v.z); o.w = f2bf(v.w);
    ((ushort4*)wsb)[g] = o;
}

// ---------------------------------------------------------------------------
// fused, 2-phase dbuf, sched_barrier-pinned pipeline:
//   per K-step: FIR_LOAD(t+1) -> STAGE_B(t+1) -> SB(0) -> MFMA(t) -> SB(0)
//   -> FIR fma+cvt+ds_write(t+1) [waitcnt vmcnt(4) lands HERE, after MFMA]
//   -> __syncthreads.
//   BM=64, BN=256, BK=64, 512 thr = 8 waves (2M x 4N), wave tile 32x64.
//   LDS 80 KB dbuf -> 2 blocks/CU. XOR swizzle (16B chunk ^ row&7): B
//   pre-swizzled at global source (linear dest, rule 21), A at ds_write.
//   bid = mt*16 + (c*2+nt): the 16 blocks sharing an inp row-block are
//   consecutive -> inp L3-served once; each XCD's wsb slice L2-resident.
// ---------------------------------------------------------------------------
__global__ __launch_bounds__(512, 4) void fused(const float* __restrict__ inp,
                                                const unsigned short* __restrict__ wsb,
                                                const float* __restrict__ bs,
                                                const float* __restrict__ Wt,
                                                const float* __restrict__ bt,
                                                float* __restrict__ out) {
    __shared__ unsigned short As0[BM * BK], As1[BM * BK];
    __shared__ unsigned short Bs0[BN * BK], Bs1[BN * BK];

    int bid = blockIdx.x;
    int mt = bid >> 4;
    int r4 = bid & 15;
    int c  = r4 >> 1;
    int nt = r4 & 1;
    int row0 = mt * BM;
    int tid = threadIdx.x, lane = tid & 63, wid = tid >> 6;
    int wm = wid >> 2, wn = wid & 3;   // 2 x 4

    // FIR weights: wave-uniform -> SGPRs
    float w[P_];
#pragma unroll
    for (int p = 0; p < P_; ++p) w[p] = Wt[c * P_ + p];

    // FIR task: 4 consecutive rows (lq*4..+3), one d-pair (dp*2, dp*2+1).
    // 244 % 4 == 0 -> a 4-row group never crosses a batch boundary.
    int lq = tid >> 5;                 // 0..15
    int dp = tid & 31;                 // 0..31
    int rg = row0 + lq * 4;
    int fb = rg / LOUT, fl = rg % LOUT;   // fl+14 <= 254 < 256: in-bounds
    const float* fir_base = inp + ((size_t)fb * L_ + fl) * D_ + dp * 2;
    int awr[4];
#pragma unroll
    for (int j = 0; j < 4; ++j) {
        int rj = lq * 4 + j;
        awr[j] = rj * BK + ((((dp >> 2) ^ (rj & 7)) << 3) + ((dp & 3) << 1));
    }

    const unsigned short* Bb = wsb + ((size_t)c * O_ + nt * BN) * D_;

    f32x4 acc[2][4];
#pragma unroll
    for (int m = 0; m < 2; ++m)
#pragma unroll
        for (int n = 0; n < 4; ++n)
            acc[m][n] = (f32x4){0.f, 0.f, 0.f, 0.f};

    unsigned short *Ac = As0, *Bc = Bs0, *An = As1, *Bn = Bs1;

#define STAGE_B(dst, dcol)                                                    \
    _Pragma("unroll")                                                         \
    for (int h = 0; h < 4; ++h) {                                             \
        int q = h * 512 + tid;                                                \
        int brow = q >> 3, cc = q & 7;                                        \
        async_copy16(Bb + (size_t)brow * D_ + (dcol) + ((cc ^ (brow & 7)) << 3), \
                     (dst) + q * 8);                                          \
    }

#define FIR_LOAD(vv, dcol)                                                    \
    _Pragma("unroll")                                                         \
    for (int j = 0; j < 15; ++j)                                              \
        vv[j] = *(const f32x2*)(fir_base + (size_t)j * D_ + (dcol));

#define FIR_STORE(vv, dst)                                                    \
    _Pragma("unroll")                                                         \
    for (int j = 0; j < 4; ++j) {                                             \
        f32x2 s = (f32x2){0.f, 0.f};                                          \
        _Pragma("unroll")                                                     \
        for (int p = 0; p < P_; ++p)                                          \
            s += vv[j + p] * w[p];      /* v_pk_fma_f32 */                    \
        ushort2 ov; ov.x = f2bf(s.x); ov.y = f2bf(s.y);                       \
        *(ushort2*)&(dst)[awr[j]] = ov;                                       \
    }

#define MFMA_STEP(Asrc, Bsrc)                                                 \
    _Pragma("unroll")                                                         \
    for (int kk = 0; kk < 2; ++kk) {                                          \
        bf16x8 af[2], bq[4];                                                  \
        _Pragma("unroll")                                                     \
        for (int m = 0; m < 2; ++m) {                                         \
            int r = wm * 32 + m * 16 + (lane & 15);                           \
            af[m] = *(const bf16x8*)&(Asrc)[r * BK +                          \
                    (((kk * 4 + (lane >> 4)) ^ (r & 7)) << 3)];               \
        }                                                                     \
        _Pragma("unroll")                                                     \
        for (int n = 0; n < 4; ++n) {                                         \
            int o = wn * 64 + n * 16 + (lane & 15);                           \
            bq[n] = *(const bf16x8*)&(Bsrc)[o * BK +                          \
                    (((kk * 4 + (lane >> 4)) ^ (o & 7)) << 3)];               \
        }                                                                     \
        _Pragma("unroll")                                                     \
        for (int m = 0; m < 2; ++m)                                           \
            _Pragma("unroll")                                                 \
            for (int n = 0; n < 4; ++n)                                       \
                acc[m][n] = __builtin_amdgcn_mfma_f32_16x16x32_bf16(          \
                    af[m], bq[n], acc[m][n], 0, 0, 0);                        \
    }

    // ---- prologue: stage t=0 ----
    {
        STAGE_B(Bc, 0)
        f32x2 v[15];
        FIR_LOAD(v, 0)
        FIR_STORE(v, Ac)
    }
    __syncthreads();

    // ---- main loop: 7 pipelined steps ----
    for (int t = 0; t < 7; ++t) {
        int dn = (t + 1) * BK;
        f32x2 v[15];
        FIR_LOAD(v, dn)                 // oldest in vmcnt queue
        STAGE_B(Bn, dn)                 // async DMA into next B buffer
        // Hard scheduler fence: nothing crosses. Loads are issued above,
        // their results first used below the SECOND fence -> waitcnt
        // vmcnt(4) lands after the MFMA cluster.
        __builtin_amdgcn_sched_barrier(0);
        MFMA_STEP(Ac, Bc)
        __builtin_amdgcn_sched_barrier(0);
        FIR_STORE(v, An)
        __syncthreads();
        unsigned short* tp;
        tp = Ac; Ac = An; An = tp;
        tp = Bc; Bc = Bn; Bn = tp;
    }

    // ---- epilogue: last K-step ----
    MFMA_STEP(Ac, Bc)

    // ---- bias + store ----
    float S = 0.f;
#pragma unroll
    for (int p = 0; p < P_; ++p) S += w[p];
    float btc = bt[c];

#pragma unroll
    for (int m = 0; m < 2; ++m) {
        int rb = row0 + wm * 32 + m * 16 + ((lane >> 4) << 2);
#pragma unroll
        for (int n = 0; n < 4; ++n) {
            int gcol = nt * BN + wn * 64 + n * 16 + (lane & 15);
            float add = bs[c * O_ + gcol] * S + btc;
#pragma unroll
            for (int i = 0; i < 4; ++i)
                out[((size_t)(rb + i) * C_ + c) * O_ + gcol] = acc[m][n][i] + add;
        }
    }
#undef STAGE_B
#undef FIR_LOAD
#undef FIR_STORE
#undef MFMA_STEP
}

// ---------------------------------------------------------------------------
// Fallback (ws too small): slow but correct, no workspace.
// ---------------------------------------------------------------------------
__global__ __launch_bounds__(256) void naive_k(const float* __restrict__ inp,
                                               const float* __restrict__ Ws,
                                               const float* __restrict__ bs,
                                               const float* __restrict__ Wt,
                                               const float* __restrict__ bt,
                                               float* __restrict__ out) {
    __shared__ float tmp[D_];
    int bid = blockIdx.x;
    int c = bid & 7; int r = bid >> 3;
    int l = r % LOUT; int b = r / LOUT;
    int tid = threadIdx.x;

    for (int d = tid; d < D_; d += 256) {
        float s = 0.f;
        for (int p = 0; p < P_; ++p)
            s += Wt[c * P_ + p] * inp[((size_t)b * L_ + l + p) * D_ + d];
        tmp[d] = s;
    }
    __syncthreads();
    float S = 0.f;
    for (int p = 0; p < P_; ++p) S += Wt[c * P_ + p];
    for (int o = tid; o < O_; o += 256) {
        const float* wrow = Ws + ((size_t)c * O_ + o) * D_;
        float s = 0.f;
        for (int d = 0; d < D_; ++d) s += wrow[d] * tmp[d];
        out[(((size_t)b * LOUT + l) * C_ + c) * O_ + o] =
            s + bs[c * O_ + o] * S + bt[c];
    }
}

extern "C" void kernel_launch(void* const* d_in, const int* in_sizes, int n_in,
                              void* d_out, int out_size, void* d_ws, size_t ws_size,
                              hipStream_t stream) {
    const float* inp = (const float*)d_in[0];
    const float* Ws  = (const float*)d_in[1];
    const float* bs  = (const float*)d_in[2];
    const float* Wt  = (const float*)d_in[3];
    const float* bt  = (const float*)d_in[4];
    float* out = (float*)d_out;

    const size_t WSBB = (size_t)C_ * O_ * D_ * 2;   // 4,194,304 bytes

    if (ws_size >= WSBB) {
        unsigned short* wsb = (unsigned short*)d_ws;
        ws_convert<<<2048, 256, 0, stream>>>(Ws, wsb);
        fused<<<NMT * NNT * C_, 512, 0, stream>>>(inp, wsb, bs, Wt, bt, out);
    } else {
        naive_k<<<B_ * LOUT * C_, 256, 0, stream>>>(inp, Ws, bs, Wt, bt, out);
    }
}

// Round 7
// 58.247 us; speedup vs baseline: 1.0638x; 1.0020x over previous
//
#include <hip/hip_runtime.h>
#include <hip/hip_bf16.h>

#define B_   16
#define L_   256
#define D_   512
#define C_   8
#define P_   12
#define LOUT 244
#define O_   512
#define GM   3904   // 61*64 exactly
#define BM   64
#define BK   32
#define NMT  61

typedef __attribute__((ext_vector_type(8))) short bf16x8;
typedef __attribute__((ext_vector_type(4))) float f32x4;
typedef __attribute__((ext_vector_type(2))) float f32x2;

__device__ __forceinline__ unsigned short f2bf(float f) {
    unsigned int u = __float_as_uint(f);
    unsigned int r = (u + 0x7FFFu + ((u >> 16) & 1u)) >> 16;
    return (unsigned short)r;
}

__device__ __forceinline__ void async_copy16(const void* g, void* l) {
    __builtin_amdgcn_global_load_lds(
        (const __attribute__((address_space(1))) unsigned int*)g,
        (__attribute__((address_space(3))) unsigned int*)l, 16, 0, 0);
}

// ---------------------------------------------------------------------------
// wsb convert: Ws f32 -> bf16 (one float4 per thread)
// ---------------------------------------------------------------------------
__global__ __launch_bounds__(256) void ws_convert(const float* __restrict__ Ws,
                                                  unsigned short* __restrict__ wsb) {
    int g = blockIdx.x * 256 + threadIdx.x;   // 524288 float4s
    float4 v = ((const float4*)Ws)[g];
    ushort4 o;
    o.x = f2bf(v.x); o.y = f2bf(v.y); o.z = f2bf(v.z); o.w = f2bf(v.w);
    ((ushort4*)wsb)[g] = o;
}

// ---------------------------------------------------------------------------
// fused: per (c, mt): out[r, :] = FIR_c(inp)[r,:] . Ws[c]^T + bias
//   Phase 1 (prologue): FIR burst -> A panel [64][512] bf16 STATIC in LDS
//     (sliding window: 12-load lead-in + 1 load/row; x1.7 redundancy; at
//      most one batch-boundary rebase per 16-row task).
//   Phase 2 (K-loop, 16 steps of BK=32): pure DMA pipeline —
//     stage B(t+1) via global_load_lds (no dest regs -> nothing to pin),
//     MFMA(t) from LDS, one barrier. B double-buffered 2x32KB.
//   LDS 128KB -> 1 block/CU, 8 waves (2m x 4n), wave tile 32x128.
//   Swizzles: A chunk^=(row&7) (2/bank per b128 group); B cell rotation
//     cell' = (cell + (o>>1))&3 pre-applied at GLOBAL source (linear DMA
//     dest, rule 21), inverted on read.
//   grid 488 = mt*8 + c -> channel per XCD; wsb panel (512KB) L2-resident.
// ---------------------------------------------------------------------------
__global__ __launch_bounds__(512, 2) void fused(const float* __restrict__ inp,
                                                const unsigned short* __restrict__ wsb,
                                                const float* __restrict__ bs,
                                                const float* __restrict__ Wt,
                                                const float* __restrict__ bt,
                                                float* __restrict__ out) {
    __shared__ unsigned short Al[BM * D_];               // 64 KB
    __shared__ unsigned short Bs0[O_ * BK], Bs1[O_ * BK]; // 32 KB each

    int bid = blockIdx.x;
    int c = bid & 7, mt = bid >> 3;
    int row0 = mt * BM;
    int tid = threadIdx.x, lane = tid & 63, wid = tid >> 6;
    int wm = wid >> 2, wn = wid & 3;       // 2 x 4 wave grid

    // FIR weights (wave-uniform -> SGPR)
    float w[P_];
#pragma unroll
    for (int p = 0; p < P_; ++p) w[p] = Wt[c * P_ + p];

    const unsigned short* Bb = wsb + (size_t)c * O_ * D_;

#define STAGE_B(dst, t)                                                       \
    _Pragma("unroll")                                                         \
    for (int h = 0; h < 4; ++h) {                                             \
        int q = h * 512 + tid;                                                \
        int o = q >> 2, cell = q & 3;                                         \
        int scell = (cell + (o >> 1)) & 3;                                    \
        async_copy16(Bb + (size_t)o * D_ + (t) * BK + scell * 8,              \
                     (dst) + q * 8);                                          \
    }

    // ---- issue first B slice DMA (overlaps the FIR burst) ----
    STAGE_B(Bs0, 0)

    // ---- FIR prologue: A panel, sliding window ----
    {
        int dp = tid & 255;                // d-pair 0..255
#pragma unroll
        for (int tk = 0; tk < 2; ++tk) {
            int rgrp = (tid >> 8) + tk * 2;      // 0..3
            int r0l = rgrp * 16;
            int gr = row0 + r0l;
            int fb = gr / LOUT, fl = gr % LOUT;
            int cross = LOUT - fl;               // j == cross -> new batch
            int fb2 = (cross < 16) ? fb + 1 : fb;
            const float* base  = inp + ((size_t)fb * L_ + fl) * D_ + dp * 2;
            const float* base2 = inp + ((size_t)fb2 * L_) * D_ + dp * 2;

            f32x2 win[P_];
            const float* cur = base;
            int off = 0;
#pragma unroll
            for (int j = 0; j < 16; ++j) {
                if (j == 0 || j == cross) {
                    const float* bp = (j == 0) ? base : base2;
                    cur = bp; off = 0;
#pragma unroll
                    for (int k = 0; k < P_; ++k)
                        win[k] = *(const f32x2*)(bp + (size_t)k * D_);
                } else {
#pragma unroll
                    for (int k = 0; k < P_ - 1; ++k) win[k] = win[k + 1];
                    win[P_ - 1] = *(const f32x2*)(cur + (size_t)(off + P_) * D_);
                    ++off;
                }
                f32x2 s = (f32x2){0.f, 0.f};
#pragma unroll
                for (int p = 0; p < P_; ++p) s += win[p] * w[p];
                int r = r0l + j;
                int ch = (dp >> 2) ^ (r & 7);    // 16B-chunk swizzle
                ushort2 ov; ov.x = f2bf(s.x); ov.y = f2bf(s.y);
                *(ushort2*)&Al[r * D_ + ch * 8 + (dp & 3) * 2] = ov;
            }
        }
    }
    __syncthreads();   // A panel + B slice 0 ready

    f32x4 acc[2][8];
#pragma unroll
    for (int m = 0; m < 2; ++m)
#pragma unroll
        for (int n = 0; n < 8; ++n)
            acc[m][n] = (f32x4){0.f, 0.f, 0.f, 0.f};

#define MFMA_STEP(t, Bc)                                                      \
    {                                                                         \
        bf16x8 af[2], bq[8];                                                  \
        _Pragma("unroll")                                                     \
        for (int m = 0; m < 2; ++m) {                                         \
            int r = wm * 32 + m * 16 + (lane & 15);                           \
            int ch = ((t) * 4 + (lane >> 4)) ^ (r & 7);                       \
            af[m] = *(const bf16x8*)&Al[r * D_ + ch * 8];                     \
        }                                                                     \
        _Pragma("unroll")                                                     \
        for (int n = 0; n < 8; ++n) {                                         \
            int o = wn * 128 + n * 16 + (lane & 15);                          \
            int cell = ((lane >> 4) - (o >> 1)) & 3;                          \
            bq[n] = *(const bf16x8*)&(Bc)[o * BK + cell * 8];                 \
        }                                                                     \
        _Pragma("unroll")                                                     \
        for (int m = 0; m < 2; ++m)                                           \
            _Pragma("unroll")                                                 \
            for (int n = 0; n < 8; ++n)                                       \
                acc[m][n] = __builtin_amdgcn_mfma_f32_16x16x32_bf16(          \
                    af[m], bq[n], acc[m][n], 0, 0, 0);                        \
    }

    // ---- K-loop: 16 steps, explicit even/odd double buffer ----
#pragma unroll
    for (int tt = 0; tt < 8; ++tt) {
        int t0 = tt * 2;
        STAGE_B(Bs1, t0 + 1)
        MFMA_STEP(t0, Bs0)
        __syncthreads();
        if (t0 + 2 < 16) STAGE_B(Bs0, t0 + 2)
        MFMA_STEP(t0 + 1, Bs1)
        __syncthreads();
    }

    // ---- bias + store ----
    float S = 0.f;
#pragma unroll
    for (int p = 0; p < P_; ++p) S += w[p];
    float btc = bt[c];

#pragma unroll
    for (int m = 0; m < 2; ++m) {
        int rb = row0 + wm * 32 + m * 16 + ((lane >> 4) << 2);
#pragma unroll
        for (int n = 0; n < 8; ++n) {
            int col = wn * 128 + n * 16 + (lane & 15);
            float add = bs[c * O_ + col] * S + btc;
#pragma unroll
            for (int i = 0; i < 4; ++i)
                out[((size_t)(rb + i) * C_ + c) * O_ + col] = acc[m][n][i] + add;
        }
    }
#undef STAGE_B
#undef MFMA_STEP
}

// ---------------------------------------------------------------------------
// Fallback (ws too small): slow but correct, no workspace.
// ---------------------------------------------------------------------------
__global__ __launch_bounds__(256) void naive_k(const float* __restrict__ inp,
                                               const float* __restrict__ Ws,
                                               const float* __restrict__ bs,
                                               const float* __restrict__ Wt,
                                               const float* __restrict__ bt,
                                               float* __restrict__ out) {
    __shared__ float tmp[D_];
    int bid = blockIdx.x;
    int c = bid & 7; int r = bid >> 3;
    int l = r % LOUT; int b = r / LOUT;
    int tid = threadIdx.x;

    for (int d = tid; d < D_; d += 256) {
        float s = 0.f;
        for (int p = 0; p < P_; ++p)
            s += Wt[c * P_ + p] * inp[((size_t)b * L_ + l + p) * D_ + d];
        tmp[d] = s;
    }
    __syncthreads();
    float S = 0.f;
    for (int p = 0; p < P_; ++p) S += Wt[c * P_ + p];
    for (int o = tid; o < O_; o += 256) {
        const float* wrow = Ws + ((size_t)c * O_ + o) * D_;
        float s = 0.f;
        for (int d = 0; d < D_; ++d) s += wrow[d] * tmp[d];
        out[(((size_t)b * LOUT + l) * C_ + c) * O_ + o] =
            s + bs[c * O_ + o] * S + bt[c];
    }
}

extern "C" void kernel_launch(void* const* d_in, const int* in_sizes, int n_in,
                              void* d_out, int out_size, void* d_ws, size_t ws_size,
                              hipStream_t stream) {
    const float* inp = (const float*)d_in[0];
    const float* Ws  = (const float*)d_in[1];
    const float* bs  = (const float*)d_in[2];
    const float* Wt  = (const float*)d_in[3];
    const float* bt  = (const float*)d_in[4];
    float* out = (float*)d_out;

    const size_t WSBB = (size_t)C_ * O_ * D_ * 2;   // 4,194,304 bytes

    if (ws_size >= WSBB) {
        unsigned short* wsb = (unsigned short*)d_ws;
        ws_convert<<<2048, 256, 0, stream>>>(Ws, wsb);
        fused<<<NMT * C_, 512, 0, stream>>>(inp, wsb, bs, Wt, bt, out);
    } else {
        naive_k<<<B_ * LOUT * C_, 256, 0, stream>>>(inp, Ws, bs, Wt, bt, out);
    }
}

// Round 8
// 55.773 us; speedup vs baseline: 1.1110x; 1.0444x over previous
//
#include <hip/hip_runtime.h>
#include <hip/hip_bf16.h>

#define B_   16
#define L_   256
#define D_   512
#define C_   8
#define P_   12
#define LOUT 244
#define O_   512
#define GM   3904   // 61*64 exactly
#define BM   64
#define BK   32
#define NMT  61
#define NSTEP 16    // D_/BK

typedef __attribute__((ext_vector_type(8))) short bf16x8;
typedef __attribute__((ext_vector_type(4))) float f32x4;
typedef __attribute__((ext_vector_type(2))) float f32x2;

__device__ __forceinline__ unsigned short f2bf(float f) {
    unsigned int u = __float_as_uint(f);
    unsigned int r = (u + 0x7FFFu + ((u >> 16) & 1u)) >> 16;
    return (unsigned short)r;
}

__device__ __forceinline__ void async_copy16(const void* g, void* l) {
    __builtin_amdgcn_global_load_lds(
        (const __attribute__((address_space(1))) unsigned int*)g,
        (__attribute__((address_space(3))) unsigned int*)l, 16, 0, 0);
}

// ---------------------------------------------------------------------------
// wsb convert: Ws f32 -> bf16 (one float4 per thread)
// ---------------------------------------------------------------------------
__global__ __launch_bounds__(256) void ws_convert(const float* __restrict__ Ws,
                                                  unsigned short* __restrict__ wsb) {
    int g = blockIdx.x * 256 + threadIdx.x;   // 524288 float4s
    float4 v = ((const float4*)Ws)[g];
    ushort4 o;
    o.x = f2bf(v.x); o.y = f2bf(v.y); o.z = f2bf(v.z); o.w = f2bf(v.w);
    ((ushort4*)wsb)[g] = o;
}

// ---------------------------------------------------------------------------
// fused: per (c, mt): out[r, :] = FIR_c(inp)[r,:] . Ws[c]^T + bias
//   A panel [64][512] bf16 static in LDS (FIR burst prologue).
//   K-loop: 16 steps of BK=32, B TRIPLE-buffered (3 x 32 KB) via
//   global_load_lds; COUNTED vmcnt (8/4/0 tail) — never drains in steady
//   state; raw s_barrier (no compiler vmcnt(0)); 2-step DMA lead time.
//   LDS = 64 + 96 = 160 KiB exactly. 512 thr = 8 waves (2m x 4n),
//   wave tile 32x128, acc[2][8].
//   Swizzles: A chunk^=(row&7); B cell rotation (cell+(o>>1))&3 applied at
//   the GLOBAL source (linear DMA dest, rule 21), inverted on ds_read.
//   grid 488 = mt*8 + c -> channel per XCD; wsb panel (512 KB) L2-resident.
// ---------------------------------------------------------------------------
__global__ __launch_bounds__(512, 2) void fused(const float* __restrict__ inp,
                                                const unsigned short* __restrict__ wsb,
                                                const float* __restrict__ bs,
                                                const float* __restrict__ Wt,
                                                const float* __restrict__ bt,
                                                float* __restrict__ out) {
    __shared__ unsigned short Al[BM * D_];     // 64 KB
    __shared__ unsigned short Bs0[O_ * BK];    // 32 KB
    __shared__ unsigned short Bs1[O_ * BK];    // 32 KB
    __shared__ unsigned short Bs2[O_ * BK];    // 32 KB

    int bid = blockIdx.x;
    int c = bid & 7, mt = bid >> 3;
    int row0 = mt * BM;
    int tid = threadIdx.x, lane = tid & 63, wid = tid >> 6;
    int wm = wid >> 2, wn = wid & 3;           // 2 x 4 wave grid

    // FIR weights (wave-uniform -> SGPR)
    float w[P_];
#pragma unroll
    for (int p = 0; p < P_; ++p) w[p] = Wt[c * P_ + p];

    const unsigned short* Bb = wsb + (size_t)c * O_ * D_;

#define STAGE_B(dst, t)                                                       \
    _Pragma("unroll")                                                         \
    for (int h = 0; h < 4; ++h) {                                             \
        int q = h * 512 + tid;                                                \
        int o = q >> 2, cellp = q & 3;                                        \
        int scell = (cellp + (o >> 1)) & 3;                                   \
        async_copy16(Bb + (size_t)o * D_ + (t) * BK + scell * 8,              \
                     (dst) + q * 8);                                          \
    }

    // ---- issue 3 stages up-front: DMA rides under the FIR burst ----
    STAGE_B(Bs0, 0)
    STAGE_B(Bs1, 1)
    STAGE_B(Bs2, 2)

    // ---- FIR prologue: A panel, sliding window (as round 7) ----
    {
        int dp = tid & 255;                // d-pair 0..255
#pragma unroll
        for (int tk = 0; tk < 2; ++tk) {
            int rgrp = (tid >> 8) + tk * 2;      // 0..3
            int r0l = rgrp * 16;
            int gr = row0 + r0l;
            int fb = gr / LOUT, fl = gr % LOUT;
            int cross = LOUT - fl;               // j == cross -> new batch
            int fb2 = (cross < 16) ? fb + 1 : fb;
            const float* base  = inp + ((size_t)fb * L_ + fl) * D_ + dp * 2;
            const float* base2 = inp + ((size_t)fb2 * L_) * D_ + dp * 2;

            f32x2 win[P_];
            const float* cur = base;
            int off = 0;
#pragma unroll
            for (int j = 0; j < 16; ++j) {
                if (j == 0 || j == cross) {
                    const float* bp = (j == 0) ? base : base2;
                    cur = bp; off = 0;
#pragma unroll
                    for (int k = 0; k < P_; ++k)
                        win[k] = *(const f32x2*)(bp + (size_t)k * D_);
                } else {
#pragma unroll
                    for (int k = 0; k < P_ - 1; ++k) win[k] = win[k + 1];
                    win[P_ - 1] = *(const f32x2*)(cur + (size_t)(off + P_) * D_);
                    ++off;
                }
                f32x2 s = (f32x2){0.f, 0.f};
#pragma unroll
                for (int p = 0; p < P_; ++p) s += win[p] * w[p];
                int r = r0l + j;
                int ch = (dp >> 2) ^ (r & 7);    // 16B-chunk swizzle
                ushort2 ov; ov.x = f2bf(s.x); ov.y = f2bf(s.y);
                *(ushort2*)&Al[r * D_ + ch * 8 + (dp & 3) * 2] = ov;
            }
        }
    }

    // stage 0 certified (1,2 = 8 insts stay in flight); FIR ds_writes done
    asm volatile("s_waitcnt vmcnt(8) lgkmcnt(0)" ::: "memory");
    __builtin_amdgcn_sched_barrier(0);
    __builtin_amdgcn_s_barrier();

    f32x4 acc[2][8];
#pragma unroll
    for (int m = 0; m < 2; ++m)
#pragma unroll
        for (int n = 0; n < 8; ++n)
            acc[m][n] = (f32x4){0.f, 0.f, 0.f, 0.f};

#define MFMA_STEP(t, Bc)                                                      \
    {                                                                         \
        bf16x8 af[2], bq[8];                                                  \
        _Pragma("unroll")                                                     \
        for (int m = 0; m < 2; ++m) {                                         \
            int r = wm * 32 + m * 16 + (lane & 15);                           \
            int ch = ((t) * 4 + (lane >> 4)) ^ (r & 7);                       \
            af[m] = *(const bf16x8*)&Al[r * D_ + ch * 8];                     \
        }                                                                     \
        _Pragma("unroll")                                                     \
        for (int n = 0; n < 8; ++n) {                                         \
            int o = wn * 128 + n * 16 + (lane & 15);                          \
            int cell = ((lane >> 4) - (o >> 1)) & 3;                          \
            bq[n] = *(const bf16x8*)&(Bc)[o * BK + cell * 8];                 \
        }                                                                     \
        _Pragma("unroll")                                                     \
        for (int m = 0; m < 2; ++m)                                           \
            _Pragma("unroll")                                                 \
            for (int n = 0; n < 8; ++n)                                       \
                acc[m][n] = __builtin_amdgcn_mfma_f32_16x16x32_bf16(          \
                    af[m], bq[n], acc[m][n], 0, 0, 0);                        \
    }

    // ---- K-loop: counted-vmcnt triple-buffer pipeline ----
    unsigned short* const bufs[3] = {Bs0, Bs1, Bs2};
#pragma unroll
    for (int t = 0; t < NSTEP; ++t) {
        MFMA_STEP(t, bufs[t % 3])
        if (t == NSTEP - 1) break;
        __builtin_amdgcn_s_barrier();       // all waves done reading buf t%3
        if (t + 3 < NSTEP) STAGE_B(bufs[t % 3], t + 3)
        // certify stage(t+1) only; keep >=2 stages in flight (T4)
        if (t < NSTEP - 3)
            asm volatile("s_waitcnt vmcnt(8)" ::: "memory");
        else if (t == NSTEP - 3)
            asm volatile("s_waitcnt vmcnt(4)" ::: "memory");
        else
            asm volatile("s_waitcnt vmcnt(0)" ::: "memory");
        __builtin_amdgcn_sched_barrier(0);  // rule 18: nothing hoists above
        __builtin_amdgcn_s_barrier();       // buf (t+1)%3 ready everywhere
    }

    // ---- bias + store ----
    float S = 0.f;
#pragma unroll
    for (int p = 0; p < P_; ++p) S += w[p];
    float btc = bt[c];

#pragma unroll
    for (int m = 0; m < 2; ++m) {
        int rb = row0 + wm * 32 + m * 16 + ((lane >> 4) << 2);
#pragma unroll
        for (int n = 0; n < 8; ++n) {
            int col = wn * 128 + n * 16 + (lane & 15);
            float add = bs[c * O_ + col] * S + btc;
#pragma unroll
            for (int i = 0; i < 4; ++i)
                out[((size_t)(rb + i) * C_ + c) * O_ + col] = acc[m][n][i] + add;
        }
    }
#undef STAGE_B
#undef MFMA_STEP
}

// ---------------------------------------------------------------------------
// Fallback (ws too small): slow but correct, no workspace.
// ---------------------------------------------------------------------------
__global__ __launch_bounds__(256) void naive_k(const float* __restrict__ inp,
                                               const float* __restrict__ Ws,
                                               const float* __restrict__ bs,
                                               const float* __restrict__ Wt,
                                               const float* __restrict__ bt,
                                               float* __restrict__ out) {
    __shared__ float tmp[D_];
    int bid = blockIdx.x;
    int c = bid & 7; int r = bid >> 3;
    int l = r % LOUT; int b = r / LOUT;
    int tid = threadIdx.x;

    for (int d = tid; d < D_; d += 256) {
        float s = 0.f;
        for (int p = 0; p < P_; ++p)
            s += Wt[c * P_ + p] * inp[((size_t)b * L_ + l + p) * D_ + d];
        tmp[d] = s;
    }
    __syncthreads();
    float S = 0.f;
    for (int p = 0; p < P_; ++p) S += Wt[c * P_ + p];
    for (int o = tid; o < O_; o += 256) {
        const float* wrow = Ws + ((size_t)c * O_ + o) * D_;
        float s = 0.f;
        for (int d = 0; d < D_; ++d) s += wrow[d] * tmp[d];
        out[(((size_t)b * LOUT + l) * C_ + c) * O_ + o] =
            s + bs[c * O_ + o] * S + bt[c];
    }
}

extern "C" void kernel_launch(void* const* d_in, const int* in_sizes, int n_in,
                              void* d_out, int out_size, void* d_ws, size_t ws_size,
                              hipStream_t stream) {
    const float* inp = (const float*)d_in[0];
    const float* Ws  = (const float*)d_in[1];
    const float* bs  = (const float*)d_in[2];
    const float* Wt  = (const float*)d_in[3];
    const float* bt  = (const float*)d_in[4];
    float* out = (float*)d_out;

    const size_t WSBB = (size_t)C_ * O_ * D_ * 2;   // 4,194,304 bytes

    if (ws_size >= WSBB) {
        unsigned short* wsb = (unsigned short*)d_ws;
        ws_convert<<<2048, 256, 0, stream>>>(Ws, wsb);
        fused<<<NMT * C_, 512, 0, stream>>>(inp, wsb, bs, Wt, bt, out);
    } else {
        naive_k<<<B_ * LOUT * C_, 256, 0, stream>>>(inp, Ws, bs, Wt, bt, out);
    }
}

// Round 9
// 41.448 us; speedup vs baseline: 1.4949x; 1.3456x over previous
//
#include <hip/hip_runtime.h>
#include <hip/hip_bf16.h>

#define B_   16
#define L_   256
#define D_   512
#define C_   8
#define P_   12
#define LOUT 244
#define O_   512
#define GM   3904   // 16*244 rows per channel
#define BM   128
#define BN   128
#define BK   64
#define NMT  31     // ceil(3904/128)
#define NNT  4

typedef __attribute__((ext_vector_type(8))) short bf16x8;
typedef __attribute__((ext_vector_type(4))) float f32x4;

__device__ __forceinline__ unsigned short f2bf(float f) {
    unsigned int u = __float_as_uint(f);
    unsigned int r = (u + 0x7FFFu + ((u >> 16) & 1u)) >> 16;
    return (unsigned short)r;
}

__device__ __forceinline__ void async_copy16(const void* g, void* l) {
    __builtin_amdgcn_global_load_lds(
        (const __attribute__((address_space(1))) unsigned int*)g,
        (__attribute__((address_space(3))) unsigned int*)l, 16, 0, 0);
}

// ---------------------------------------------------------------------------
// prep (round-2 verbatim, verified):
//   blocks [0,976):  tmp[c][b][l][d] = sum_p Wt[c,p]*inp[b,l+p,d] (bf16);
//                    one inp read serves all 8 channels.
//   blocks [976,3024): Ws f32 -> bf16.
// ---------------------------------------------------------------------------
__global__ __launch_bounds__(256) void prep(const float* __restrict__ inp,
                                            const float* __restrict__ Ws,
                                            const float* __restrict__ Wt,
                                            unsigned short* __restrict__ tmp,
                                            unsigned short* __restrict__ wsb) {
    int bid = blockIdx.x;
    int tid = threadIdx.x;

    if (bid >= 976) {                       // ---- Ws convert path ----
        int g = (bid - 976) * 256 + tid;    // 524288 float4s
        float4 v = ((const float4*)Ws)[g];
        ushort4 o;
        o.x = f2bf(v.x); o.y = f2bf(v.y); o.z = f2bf(v.z); o.w = f2bf(v.w);
        ((ushort4*)wsb)[g] = o;
        return;
    }

    // ---- FIR path ----
    __shared__ float wt_s[C_][P_];
    if (tid < C_ * P_) wt_s[tid / P_][tid % P_] = Wt[tid];
    __syncthreads();

    int b = bid / 61, lg = bid % 61;
    int l0 = lg * 4;
    int d0 = tid * 2;

    float2 rows[15];
    const float* ibase = inp + ((size_t)b * L_ + l0) * D_ + d0;
#pragma unroll
    for (int j = 0; j < 15; ++j)
        rows[j] = *(const float2*)(ibase + (size_t)j * D_);

#pragma unroll
    for (int c = 0; c < C_; ++c) {
        float w[P_];
#pragma unroll
        for (int p = 0; p < P_; ++p) w[p] = wt_s[c][p];
        unsigned short* ob = tmp + (((size_t)(c * B_ + b)) * LOUT + l0) * D_ + d0;
#pragma unroll
        for (int j = 0; j < 4; ++j) {
            float vx = 0.f, vy = 0.f;
#pragma unroll
            for (int p = 0; p < P_; ++p) {
                vx += w[p] * rows[j + p].x;
                vy += w[p] * rows[j + p].y;
            }
            ushort2 ov; ov.x = f2bf(vx); ov.y = f2bf(vy);
            *(ushort2*)(ob + (size_t)j * D_) = ov;
        }
    }
}

// ---------------------------------------------------------------------------
// gemm: per (c,mt,nt): out[r,o] = tmp_c[r,:] . Ws_c[o,:] + S*bs + bt
//   128x128 tile, BK=64, 512 thr = 8 waves (2m x 4n), wave tile 64x32,
//   acc[4][2]. LDS dbuf 64 KB -> 2 blocks/CU (TLP hides latency, m114).
//   K-loop: counted-vmcnt double buffer (round-8 verified sequence):
//     MFMA(t) -> s_barrier -> STAGE(t+2) -> vmcnt(4) (0 only at tail)
//     -> sched_barrier(0) -> s_barrier.
//   Staging: global_load_lds x16, linear dest + source-XOR swizzle
//     (chunk ^ row&7), reads apply same XOR (rounds 4-8 verified).
//   bid = (mt*4+nt)*8 + c: channel per XCD (wsb panel L2-resident);
//     nt-siblings time-adjacent -> tmp rows L2-reused.
// ---------------------------------------------------------------------------
__global__ __launch_bounds__(512, 4) void gemm_k(const unsigned short* __restrict__ tmp,
                                                 const unsigned short* __restrict__ wsb,
                                                 const float* __restrict__ bs,
                                                 const float* __restrict__ Wt,
                                                 const float* __restrict__ bt,
                                                 float* __restrict__ out) {
    __shared__ unsigned short As0[BM * BK], As1[BM * BK];   // 16 KB each
    __shared__ unsigned short Bs0[BN * BK], Bs1[BN * BK];   // 16 KB each

    int bid = blockIdx.x;
    int c  = bid & 7;
    int t2 = bid >> 3;                 // 0..123
    int nt = t2 & 3;
    int mt = t2 >> 2;                  // 0..30
    int row0 = mt * BM;
    int o0   = nt * BN;
    int tid = threadIdx.x, lane = tid & 63, wid = tid >> 6;
    int wm = wid >> 2, wn = wid & 3;   // 2 x 4 wave grid; wave tile 64x32

    const unsigned short* Ab = tmp + (size_t)c * GM * D_;
    const unsigned short* Bb = wsb + ((size_t)c * O_ + o0) * D_;

    f32x4 acc[4][2];
#pragma unroll
    for (int m = 0; m < 4; ++m)
#pragma unroll
        for (int n = 0; n < 2; ++n)
            acc[m][n] = (f32x4){0.f, 0.f, 0.f, 0.f};

    unsigned short *Ac = As0, *Bc = Bs0, *An = As1, *Bn = Bs1;

    // per STAGE: 1024 chunks per matrix, 2 per thread per matrix (4 glds)
#define STAGE(dstA, dstB, kb)                                                 \
    _Pragma("unroll")                                                         \
    for (int h = 0; h < 2; ++h) {                                             \
        int q = h * 512 + tid;                                                \
        int row = q >> 3, cc = q & 7;                                         \
        int sc = cc ^ (row & 7);                                              \
        int ar = row0 + row; if (ar > GM - 1) ar = GM - 1;                    \
        async_copy16(Ab + (size_t)ar * D_ + (kb) + sc * 8, (dstA) + q * 8);   \
        async_copy16(Bb + (size_t)row * D_ + (kb) + sc * 8, (dstB) + q * 8);  \
    }

#define MFMA_STEP(Asrc, Bsrc)                                                 \
    _Pragma("unroll")                                                         \
    for (int kk = 0; kk < 2; ++kk) {                                          \
        bf16x8 af[4], bq[2];                                                  \
        _Pragma("unroll")                                                     \
        for (int m = 0; m < 4; ++m) {                                         \
            int r = wm * 64 + m * 16 + (lane & 15);                           \
            af[m] = *(const bf16x8*)&(Asrc)[r * BK +                          \
                    (((kk * 4 + (lane >> 4)) ^ (r & 7)) << 3)];               \
        }                                                                     \
        _Pragma("unroll")                                                     \
        for (int n = 0; n < 2; ++n) {                                         \
            int o = wn * 32 + n * 16 + (lane & 15);                           \
            bq[n] = *(const bf16x8*)&(Bsrc)[o * BK +                          \
                    (((kk * 4 + (lane >> 4)) ^ (o & 7)) << 3)];               \
        }                                                                     \
        _Pragma("unroll")                                                     \
        for (int m = 0; m < 4; ++m)                                           \
            _Pragma("unroll")                                                 \
            for (int n = 0; n < 2; ++n)                                       \
                acc[m][n] = __builtin_amdgcn_mfma_f32_16x16x32_bf16(          \
                    af[m], bq[n], acc[m][n], 0, 0, 0);                        \
    }

    // ---- prologue: stage steps 0 and 1; certify 0, keep 1 in flight ----
    STAGE(Ac, Bc, 0)
    STAGE(An, Bn, BK)
    asm volatile("s_waitcnt vmcnt(4)" ::: "memory");
    __builtin_amdgcn_sched_barrier(0);
    __builtin_amdgcn_s_barrier();

    // ---- K-loop: 8 steps, counted vmcnt (round-8 verified pattern) ----
#pragma unroll
    for (int t = 0; t < 8; ++t) {
        MFMA_STEP(Ac, Bc)
        if (t == 7) break;
        __builtin_amdgcn_s_barrier();          // all waves done reading buf t&1
        if (t + 2 < 8) STAGE(Ac, Bc, (t + 2) * BK)   // refill the buffer just read
        if (t < 6)
            asm volatile("s_waitcnt vmcnt(4)" ::: "memory");  // certify t+1
        else
            asm volatile("s_waitcnt vmcnt(0)" ::: "memory");  // tail: certify 7
        __builtin_amdgcn_sched_barrier(0);
        __builtin_amdgcn_s_barrier();          // buf (t+1)&1 ready for all
        unsigned short* tp;
        tp = Ac; Ac = An; An = tp;
        tp = Bc; Bc = Bn; Bn = tp;
    }

    // ---- bias + store ----
    float S = 0.f;
#pragma unroll
    for (int p = 0; p < P_; ++p) S += Wt[c * P_ + p];
    float btc = bt[c];

#pragma unroll
    for (int m = 0; m < 4; ++m) {
        int rb = row0 + wm * 64 + m * 16 + ((lane >> 4) << 2);
#pragma unroll
        for (int n = 0; n < 2; ++n) {
            int col = o0 + wn * 32 + n * 16 + (lane & 15);
            float add = bs[c * O_ + col] * S + btc;
#pragma unroll
            for (int i = 0; i < 4; ++i) {
                int r = rb + i;
                if (r < GM)
                    out[((size_t)r * C_ + c) * O_ + col] = acc[m][n][i] + add;
            }
        }
    }
#undef STAGE
#undef MFMA_STEP
}

// ---------------------------------------------------------------------------
// Fallback (ws too small): slow but correct, no workspace.
// ---------------------------------------------------------------------------
__global__ __launch_bounds__(256) void naive_k(const float* __restrict__ inp,
                                               const float* __restrict__ Ws,
                                               const float* __restrict__ bs,
                                               const float* __restrict__ Wt,
                                               const float* __restrict__ bt,
                                               float* __restrict__ out) {
    __shared__ float tmp[D_];
    int bid = blockIdx.x;
    int c = bid & 7; int r = bid >> 3;
    int l = r % LOUT; int b = r / LOUT;
    int tid = threadIdx.x;

    for (int d = tid; d < D_; d += 256) {
        float s = 0.f;
        for (int p = 0; p < P_; ++p)
            s += Wt[c * P_ + p] * inp[((size_t)b * L_ + l + p) * D_ + d];
        tmp[d] = s;
    }
    __syncthreads();
    float S = 0.f;
    for (int p = 0; p < P_; ++p) S += Wt[c * P_ + p];
    for (int o = tid; o < O_; o += 256) {
        const float* wrow = Ws + ((size_t)c * O_ + o) * D_;
        float s = 0.f;
        for (int d = 0; d < D_; ++d) s += wrow[d] * tmp[d];
        out[(((size_t)b * LOUT + l) * C_ + c) * O_ + o] =
            s + bs[c * O_ + o] * S + bt[c];
    }
}

extern "C" void kernel_launch(void* const* d_in, const int* in_sizes, int n_in,
                              void* d_out, int out_size, void* d_ws, size_t ws_size,
                              hipStream_t stream) {
    const float* inp = (const float*)d_in[0];
    const float* Ws  = (const float*)d_in[1];
    const float* bs  = (const float*)d_in[2];
    const float* Wt  = (const float*)d_in[3];
    const float* bt  = (const float*)d_in[4];
    float* out = (float*)d_out;

    const size_t TMPB = (size_t)C_ * GM * D_ * 2;   // 31,981,568
    const size_t WSBB = (size_t)C_ * O_ * D_ * 2;   //  4,194,304

    if (ws_size >= TMPB + WSBB) {
        unsigned short* tmpb = (unsigned short*)d_ws;
        unsigned short* wsb  = (unsigned short*)((char*)d_ws + TMPB);
        prep<<<3024, 256, 0, stream>>>(inp, Ws, Wt, tmpb, wsb);
        gemm_k<<<NMT * NNT * C_, 512, 0, stream>>>(tmpb, wsb, bs, Wt, bt, out);
    } else {
        naive_k<<<B_ * LOUT * C_, 256, 0, stream>>>(inp, Ws, bs, Wt, bt, out);
    }
}